// Round 9
// baseline (283.313 us; speedup 1.0000x reference)
//
#include <hip/hip_runtime.h>
#include <math.h>

#define B_   256
#define QL_  16
#define DL_  512
#define ED_  300
#define K2_  240
#define K4_  192
#define NEGINF (-3.402823466e38f)

__device__ __forceinline__ float sigf(float x){ return 1.0f/(1.0f+__expf(-x)); }

__device__ __forceinline__ float dot16(const float (&a)[16], const float* w){
  float s = 0.f;
  #pragma unroll
  for (int i=0;i<4;i++){
    float4 ww = *(const float4*)(w + 4*i);
    s = fmaf(a[4*i+0], ww.x, s);
    s = fmaf(a[4*i+1], ww.y, s);
    s = fmaf(a[4*i+2], ww.z, s);
    s = fmaf(a[4*i+3], ww.w, s);
  }
  return s;
}

// block-wide bitonic, descending by value, ties -> lower index first
template<int N, int T>
__device__ void bitonic_desc(float* v, int* id){
  const int tid = threadIdx.x;
  for (int k = 2; k <= N; k <<= 1){
    for (int j = k >> 1; j > 0; j >>= 1){
      __syncthreads();
      for (int i = tid; i < N; i += T){
        const int l = i ^ j;
        if (l > i){
          const float vi = v[i], vl = v[l];
          const int ii = id[i], il = id[l];
          const bool before_l = (vl > vi) || (vl == vi && il < ii);
          const bool up = ((i & k) == 0);
          if (up == before_l){ v[i]=vl; v[l]=vi; id[i]=il; id[l]=ii; }
        }
      }
    }
  }
  __syncthreads();
}

// in-register wave-level bitonic sort, descending, values only
template<int NREG>
__device__ __forceinline__ void wave_sort_desc(float (&v)[NREG], int lane){
  constexpr int TOT = NREG*64;
  #pragma unroll
  for (int k = 2; k <= TOT; k <<= 1){
    #pragma unroll
    for (int j = k>>1; j > 0; j >>= 1){
      if (j >= 64){
        const int jr = j >> 6;
        #pragma unroll
        for (int r = 0; r < NREG; r++){
          if ((r & jr) == 0){
            const int p = r | jr;
            const bool desc = (((r*64) & k) == 0);
            const float a = v[r], c = v[p];
            const float mx = fmaxf(a,c), mn = fminf(a,c);
            v[r] = desc ? mx : mn;
            v[p] = desc ? mn : mx;
          }
        }
      } else {
        #pragma unroll
        for (int r = 0; r < NREG; r++){
          const float ov = __shfl_xor(v[r], j);
          const bool desc = (((r*64 + lane) & k) == 0);
          const bool lower = (lane & j) == 0;
          v[r] = (lower == desc) ? fmaxf(v[r], ov) : fminf(v[r], ov);
        }
      }
    }
  }
}

// ---------------- K: the whole net for one batch item, 1024 threads --------
__global__ __launch_bounds__(1024) void k_all(
    const float* __restrict__ emb, const int* __restrict__ qtok,
    const int* __restrict__ dtok, const int* __restrict__ dids,
    const float* __restrict__ dadj,
    const float* __restrict__ Wg1, const float* __restrict__ bg1,
    const float* __restrict__ p1w, const float* __restrict__ p1b,
    const float* __restrict__ wg2, const float* __restrict__ bg2,
    const float* __restrict__ Wg3, const float* __restrict__ bg3,
    const float* __restrict__ p2w, const float* __restrict__ p2b,
    const float* __restrict__ wg4, const float* __restrict__ bg4,
    const float* __restrict__ l1w, const float* __restrict__ l1b,
    const float* __restrict__ l2w, const float* __restrict__ l2b,
    const float* __restrict__ l3w, const float* __restrict__ l3b,
    const float* __restrict__ idf, const float* __restrict__ gw,
    const float* __restrict__ gb,
    float* __restrict__ adjnew, float* __restrict__ outp)
{
  extern __shared__ float sm[];
  float* ql   = sm;              // 16*304
  float* fx   = ql + 4864;       // [512][20]
  float* repl = fx + 10240;      // [512][20]
  float* wl   = repl + 10240;    // 1536
  float* bl   = wl + 1536;       // 96
  float* pwl  = bl + 96;         // 16
  float* xv   = pwl + 16;        // 512
  float* sval = xv + 512;        // 512
  int*   sidx = (int*)(sval + 512);  // 512
  int*   il   = sidx + 512;      // 240
  float* attl = (float*)(il + 240);  // 16*120
  float* rel1 = attl + 1920;     // 1024
  float* rel2 = rel1 + 1024;     // 512
  float* qinv = rel2 + 512;      // 16
  int*   toks = (int*)(qinv + 16);   // 512

  const int tid = threadIdx.x, b = blockIdx.x;
  const int wave = tid >> 6, lane = tid & 63;
  const float* abase = dadj + (size_t)dids[b]*512*512;

  // ---- PA: stage q-embeddings, doc tokens, ggnn1 weights ----
  for (int idx = tid; idx < 16*ED_; idx += 1024){
    const int q = idx / ED_, e = idx - q*ED_;
    ql[q*304+e] = emb[(size_t)qtok[(size_t)b*QL_ + q]*ED_ + e];
  }
  if (tid < 512) toks[tid] = dtok[(size_t)b*DL_ + tid];
  for (int idx = tid; idx < 1536; idx += 1024) wl[idx] = Wg1[idx];
  if (tid >= 1024-96 && tid < 1024) bl[tid-(1024-96)] = bg1[tid-(1024-96)];
  if (tid >= 512 && tid < 528) pwl[tid-512] = p1w[tid-512];
  __syncthreads();
  if (tid < 256){
    const int q = tid >> 4, s = tid & 15;
    float ss = 0.f;
    for (int e=s;e<ED_;e+=16){ const float x = ql[q*304+e]; ss = fmaf(x,x,ss); }
    ss += __shfl_xor(ss,1); ss += __shfl_xor(ss,2);
    ss += __shfl_xor(ss,4); ss += __shfl_xor(ss,8);
    if (s == 0) qinv[q] = 1.f/(sqrtf(ss)+1e-9f);
  }
  __syncthreads();

  // ---- PB: cosine feat -> fx[d][q]; 2 rows per 4-lane group, 3-deep pf ----
  {
    const int g = tid>>2, sub = tid&3;
    const float* e0p = emb + (size_t)toks[2*g+0]*ED_;
    const float* e1p = emb + (size_t)toks[2*g+1]*ED_;
    float acc[2][16];
    float ssr[2] = {0.f,0.f};
    #pragma unroll
    for (int r=0;r<2;r++)
      #pragma unroll
      for (int q=0;q<16;q++) acc[r][q] = 0.f;
    // overreach loads (j up to 83 -> offset <= 336+3 floats) stay in-bounds:
    // tok <= 49999, emb has 50001 rows of 300 floats.
    float4 a0 = *(const float4*)(e0p + 4*(sub));
    float4 a1 = *(const float4*)(e1p + 4*(sub));
    float4 b0 = *(const float4*)(e0p + 4*(sub+4));
    float4 b1 = *(const float4*)(e1p + 4*(sub+4));
    for (int i=0;i<19;i++){
      const int jn = sub + 4*(i+2);
      float4 c0v = *(const float4*)(e0p + 4*jn);
      float4 c1v = *(const float4*)(e1p + 4*jn);
      const int j = sub + 4*i;
      if (j < 75){
        const int e0 = 4*j;
        ssr[0] = fmaf(a0.x,a0.x, fmaf(a0.y,a0.y, fmaf(a0.z,a0.z, fmaf(a0.w,a0.w, ssr[0]))));
        ssr[1] = fmaf(a1.x,a1.x, fmaf(a1.y,a1.y, fmaf(a1.z,a1.z, fmaf(a1.w,a1.w, ssr[1]))));
        #pragma unroll
        for (int q=0;q<16;q++){
          float4 qv = *(const float4*)(&ql[q*304 + e0]);
          acc[0][q] = fmaf(a0.x,qv.x, fmaf(a0.y,qv.y, fmaf(a0.z,qv.z, fmaf(a0.w,qv.w, acc[0][q]))));
          acc[1][q] = fmaf(a1.x,qv.x, fmaf(a1.y,qv.y, fmaf(a1.z,qv.z, fmaf(a1.w,qv.w, acc[1][q]))));
        }
      }
      a0 = b0; a1 = b1; b0 = c0v; b1 = c1v;
    }
    #pragma unroll
    for (int r=0;r<2;r++){
      #pragma unroll
      for (int q=0;q<16;q++){
        float v = acc[r][q];
        v += __shfl_xor(v, 1);
        v += __shfl_xor(v, 2);
        acc[r][q] = v;
      }
      float sv = ssr[r];
      sv += __shfl_xor(sv, 1);
      sv += __shfl_xor(sv, 2);
      ssr[r] = sv;
    }
    if (sub < 2){
      const int d = 2*g + sub;
      const float ssd = sub ? ssr[1] : ssr[0];
      const float invd = 1.f/(sqrtf(ssd)+1e-9f);
      float vs[16];
      #pragma unroll
      for (int q=0;q<16;q++){
        const float v = sub ? acc[1][q] : acc[0][q];
        vs[q] = v * invd * qinv[q];
      }
      float* fo = &fx[(size_t)d*20];
      *(float4*)(fo+0)  = make_float4(vs[0],vs[1],vs[2],vs[3]);
      *(float4*)(fo+4)  = make_float4(vs[4],vs[5],vs[6],vs[7]);
      *(float4*)(fo+8)  = make_float4(vs[8],vs[9],vs[10],vs[11]);
      *(float4*)(fo+12) = make_float4(vs[12],vs[13],vs[14],vs[15]);
    }
  }
  __syncthreads();

  // ---- PD: waves 0-7 gemm512+gate (4 rows/group, 2-deep pf) || 8-15 topk0 --
  if (wave < 8){
    const int g = tid >> 2, sub = tid & 3;    // g in [0,128)
    const int mb = 4*g;
    const float* r0 = abase + (size_t)mb * 512;
    float acc[4][16];
    #pragma unroll
    for (int r=0;r<4;r++)
      #pragma unroll
      for (int q=0;q<16;q++) acc[r][q] = 0.f;
    int kk = sub*4;
    float4 c0 = *(const float4*)(r0 + kk);
    float4 c1 = *(const float4*)(r0 + 512 + kk);
    float4 c2 = *(const float4*)(r0 + 2*512 + kk);
    float4 c3 = *(const float4*)(r0 + 3*512 + kk);
    for (int i = 0; i < 32; i++){
      const int kn = kk + ((i < 31) ? 16 : 0);
      float4 n0 = *(const float4*)(r0 + kn);
      float4 n1 = *(const float4*)(r0 + 512 + kn);
      float4 n2 = *(const float4*)(r0 + 2*512 + kn);
      float4 n3 = *(const float4*)(r0 + 3*512 + kn);
      const float av[4][4] = {{c0.x,c0.y,c0.z,c0.w},{c1.x,c1.y,c1.z,c1.w},
                              {c2.x,c2.y,c2.z,c2.w},{c3.x,c3.y,c3.z,c3.w}};
      #pragma unroll
      for (int c = 0; c < 4; c++){
        const float* fr = &fx[(size_t)(kk + c)*20];
        float4 q0 = *(const float4*)(fr);
        float4 q1 = *(const float4*)(fr+4);
        float4 q2 = *(const float4*)(fr+8);
        float4 q3 = *(const float4*)(fr+12);
        const float qv[16] = {q0.x,q0.y,q0.z,q0.w, q1.x,q1.y,q1.z,q1.w,
                              q2.x,q2.y,q2.z,q2.w, q3.x,q3.y,q3.z,q3.w};
        #pragma unroll
        for (int r = 0; r < 4; r++){
          const float a_ = av[r][c];
          #pragma unroll
          for (int q = 0; q < 16; q++)
            acc[r][q] = fmaf(a_, qv[q], acc[r][q]);
        }
      }
      c0 = n0; c1 = n1; c2 = n2; c3 = n3;
      kk += 16;
    }
    #pragma unroll
    for (int r=0;r<4;r++)
      #pragma unroll
      for (int q=0;q<16;q++){
        float v = acc[r][q];
        v += __shfl_xor(v, 1);
        v += __shfl_xor(v, 2);
        acc[r][q] = v;
      }
    const int m = mb + sub;
    float a[16], x[16];
    #pragma unroll
    for (int q=0;q<16;q++)
      a[q] = (sub==0)?acc[0][q]:(sub==1)?acc[1][q]:(sub==2)?acc[2][q]:acc[3][q];
    {
      const float* xr = &fx[(size_t)m*20];
      float4 x0 = *(const float4*)(xr),   x1 = *(const float4*)(xr+4);
      float4 x2v = *(const float4*)(xr+8), x3 = *(const float4*)(xr+12);
      x[0]=x0.x; x[1]=x0.y; x[2]=x0.z; x[3]=x0.w;
      x[4]=x1.x; x[5]=x1.y; x[6]=x1.z; x[7]=x1.w;
      x[8]=x2v.x; x[9]=x2v.y; x[10]=x2v.z; x[11]=x2v.w;
      x[12]=x3.x; x[13]=x3.y; x[14]=x3.z; x[15]=x3.w;
    }
    float z[16], rr[16];
    #pragma unroll
    for (int q=0;q<16;q++){
      const float s0 = bl[q] + bl[16+q]
                     + dot16(a, &wl[q*16]) + dot16(x, &wl[256 + q*16]);
      z[q] = sigf(s0);
      const float s1 = bl[32+q] + bl[48+q]
                     + dot16(a, &wl[512 + q*16]) + dot16(x, &wl[768 + q*16]);
      rr[q] = sigf(s1);
    }
    float rx[16];
    #pragma unroll
    for (int q=0;q<16;q++) rx[q] = rr[q]*x[q];
    float out[16]; float xp = 0.f;
    #pragma unroll
    for (int q=0;q<16;q++){
      const float s = bl[64+q] + bl[80+q]
                    + dot16(a, &wl[1024 + q*16]) + dot16(rx, &wl[1280 + q*16]);
      const float h = fmaxf(s, 0.f);
      const float o = h*z[q] + x[q]*(1.f - z[q]);
      out[q] = o;
      xp = fmaf(o, pwl[q], xp);
    }
    float* rp = &repl[(size_t)m*20];
    *(float4*)(rp+0)  = make_float4(out[0],out[1],out[2],out[3]);
    *(float4*)(rp+4)  = make_float4(out[4],out[5],out[6],out[7]);
    *(float4*)(rp+8)  = make_float4(out[8],out[9],out[10],out[11]);
    *(float4*)(rp+12) = make_float4(out[12],out[13],out[14],out[15]);
    xv[m] = xp + p1b[0];
  } else {
    // topk0: 2 q per wave (waves 8-15 -> q 0..15), concurrent with gemm
    #pragma unroll
    for (int t=0;t<2;t++){
      const int q = (wave-8)*2 + t;
      float v[8];
      #pragma unroll
      for (int r=0;r<8;r++) v[r] = fx[(size_t)(lane + 64*r)*20 + q];
      wave_sort_desc<8>(v, lane);
      if (lane < 40) attl[q*120 + lane] = v[0];
    }
  }
  __syncthreads();

  // ---- PE: score1 = gate(adj@x2, x2), all 16 waves (adj L2/L3-hot) ----
  {
    const int g = tid >> 2, sub = tid & 3;
    const float w0=wg2[0],w1=wg2[1],w2=wg2[2],w3=wg2[3],w4=wg2[4],w5=wg2[5];
    const float c0=bg2[0],c1=bg2[1],c2=bg2[2],c3=bg2[3],c4=bg2[4],c5=bg2[5];
    #pragma unroll
    for (int pp=0; pp<2; pp++){
      const int m = pp*256 + g;
      const float* row = abase + (size_t)m*512;
      float s = 0.f;
      #pragma unroll
      for (int ii=0; ii<8; ii++){
        const int k0 = ii*64 + sub*4;
        float4 a0 = *(const float4*)(row + k0);
        float4 a1 = *(const float4*)(row + k0 + 16);
        float4 a2 = *(const float4*)(row + k0 + 32);
        float4 a3 = *(const float4*)(row + k0 + 48);
        float4 x0 = *(const float4*)(&xv[k0]);
        float4 x1 = *(const float4*)(&xv[k0+16]);
        float4 x2v = *(const float4*)(&xv[k0+32]);
        float4 x3 = *(const float4*)(&xv[k0+48]);
        s = fmaf(a0.x,x0.x,s); s = fmaf(a0.y,x0.y,s);
        s = fmaf(a0.z,x0.z,s); s = fmaf(a0.w,x0.w,s);
        s = fmaf(a1.x,x1.x,s); s = fmaf(a1.y,x1.y,s);
        s = fmaf(a1.z,x1.z,s); s = fmaf(a1.w,x1.w,s);
        s = fmaf(a2.x,x2v.x,s); s = fmaf(a2.y,x2v.y,s);
        s = fmaf(a2.z,x2v.z,s); s = fmaf(a2.w,x2v.w,s);
        s = fmaf(a3.x,x3.x,s); s = fmaf(a3.y,x3.y,s);
        s = fmaf(a3.z,x3.z,s); s = fmaf(a3.w,x3.w,s);
      }
      s += __shfl_xor(s,1); s += __shfl_xor(s,2);
      if (sub == 0){
        const float x = xv[m];
        const float z = sigf(fmaf(s,w0,c0) + fmaf(x,w1,c1));
        const float r = sigf(fmaf(s,w2,c2) + fmaf(x,w3,c3));
        const float h = fmaxf(fmaf(s,w4,c4) + fmaf(r*x,w5,c5), 0.f);
        sval[m] = h*z + x*(1.f - z);
        sidx[m] = m;
      }
    }
  }
  bitonic_desc<512,1024>(sval, sidx);

  // ---- PG: gather att_x1 into fx rows 0..239 (from LDS repl), record il ----
  if (tid < K2_){
    const int rowi = sidx[tid];
    il[tid] = rowi;
    const float tv = tanhf(sval[tid]);
    const float* rr = &repl[(size_t)rowi*20];
    float4 r0 = *(const float4*)(rr),   r1 = *(const float4*)(rr+4);
    float4 r2 = *(const float4*)(rr+8), r3 = *(const float4*)(rr+12);
    float* o = &fx[(size_t)tid*20];
    *(float4*)(o+0)  = make_float4(tv*r0.x,tv*r0.y,tv*r0.z,tv*r0.w);
    *(float4*)(o+4)  = make_float4(tv*r1.x,tv*r1.y,tv*r1.z,tv*r1.w);
    *(float4*)(o+8)  = make_float4(tv*r2.x,tv*r2.y,tv*r2.z,tv*r2.w);
    *(float4*)(o+12) = make_float4(tv*r3.x,tv*r3.y,tv*r3.z,tv*r3.w);
  }
  __syncthreads();

  // ---- PH: waves 0-11 subadj gather || waves 12-15 Wg3 staging + att1 ----
  if (wave < 12){
    int jc[4];
    #pragma unroll
    for (int c=0;c<4;c++){
      const int j = lane + 64*c;
      jc[c] = (j < K2_) ? il[j] : 0;
    }
    #pragma unroll
    for (int p=0;p<20;p++){
      const int r = wave*20 + p;
      const float* row = abase + (size_t)il[r]*512;
      float* orow = adjnew + ((size_t)b*K2_ + r)*K2_;
      #pragma unroll
      for (int c=0;c<4;c++){
        const int j = lane + 64*c;
        if (j < K2_) orow[j] = row[jc[c]];
      }
    }
  } else {
    const int t4 = tid - 768;
    for (int idx = t4; idx < 1536; idx += 256) wl[idx] = Wg3[idx];
    if (t4 < 96) bl[t4] = bg3[t4];
    if (t4 < 16) pwl[t4] = p2w[t4];
    #pragma unroll
    for (int t=0;t<4;t++){
      const int q = (wave-12)*4 + t;
      float v[4];
      #pragma unroll
      for (int r=0;r<4;r++){
        const int idx = lane + 64*r;
        v[r] = (idx < K2_) ? fx[(size_t)idx*20 + q] : NEGINF;
      }
      wave_sort_desc<4>(v, lane);
      if (lane < 40) attl[q*120 + 40 + lane] = v[0];
    }
  }
  __syncthreads();

  // ---- PI: gemm240 + matrix gate -> repl, xv(=x4) ----
  {
    const int g = tid >> 2, sub = tid & 3;
    if (g < K2_){
      const int m = g;
      const float* r0 = adjnew + ((size_t)b*K2_ + m)*K2_;
      float acc[16];
      #pragma unroll
      for (int q=0;q<16;q++) acc[q] = 0.f;
      for (int i=0;i<15;i++){
        const int kk = i*16 + sub*4;
        float4 a4 = *(const float4*)(r0 + kk);
        const float av[4] = {a4.x, a4.y, a4.z, a4.w};
        #pragma unroll
        for (int c=0;c<4;c++){
          const float* fr = &fx[(size_t)(kk + c)*20];
          float4 q0 = *(const float4*)(fr);
          float4 q1 = *(const float4*)(fr+4);
          float4 q2 = *(const float4*)(fr+8);
          float4 q3 = *(const float4*)(fr+12);
          const float qv[16] = {q0.x,q0.y,q0.z,q0.w, q1.x,q1.y,q1.z,q1.w,
                                q2.x,q2.y,q2.z,q2.w, q3.x,q3.y,q3.z,q3.w};
          #pragma unroll
          for (int q=0;q<16;q++)
            acc[q] = fmaf(av[c], qv[q], acc[q]);
        }
      }
      #pragma unroll
      for (int q=0;q<16;q++){
        float v = acc[q];
        v += __shfl_xor(v, 1);
        v += __shfl_xor(v, 2);
        acc[q] = v;
      }
      float x[16];
      {
        const float* xr = &fx[(size_t)m*20];
        float4 x0 = *(const float4*)(xr),   x1 = *(const float4*)(xr+4);
        float4 x2v = *(const float4*)(xr+8), x3 = *(const float4*)(xr+12);
        x[0]=x0.x; x[1]=x0.y; x[2]=x0.z; x[3]=x0.w;
        x[4]=x1.x; x[5]=x1.y; x[6]=x1.z; x[7]=x1.w;
        x[8]=x2v.x; x[9]=x2v.y; x[10]=x2v.z; x[11]=x2v.w;
        x[12]=x3.x; x[13]=x3.y; x[14]=x3.z; x[15]=x3.w;
      }
      float rx[16];
      #pragma unroll
      for (int q=0;q<16;q++){
        const float s1 = bl[32+q] + bl[48+q]
                       + dot16(acc, &wl[512 + q*16]) + dot16(x, &wl[768 + q*16]);
        rx[q] = sigf(s1) * x[q];
      }
      float xp = 0.f;
      #pragma unroll
      for (int j=0;j<4;j++){
        const int q = sub*4 + j;
        const float s0 = bl[q] + bl[16+q]
                       + dot16(acc, &wl[q*16]) + dot16(x, &wl[256 + q*16]);
        const float z = sigf(s0);
        const float s = bl[64+q] + bl[80+q]
                      + dot16(acc, &wl[1024 + q*16]) + dot16(rx, &wl[1280 + q*16]);
        const float h = fmaxf(s, 0.f);
        const float o = h*z + x[q]*(1.f - z);
        repl[(size_t)m*20 + q] = o;
        xp = fmaf(o, pwl[q], xp);
      }
      xp += __shfl_xor(xp,1); xp += __shfl_xor(xp,2);
      if (sub == 0) xv[m] = xp + p2b[0];
    }
  }
  __syncthreads();

  // ---- PJ: score2 ----
  {
    const int g = tid >> 2, sub = tid & 3;
    const float w0=wg4[0],w1=wg4[1],w2=wg4[2],w3=wg4[3],w4=wg4[4],w5=wg4[5];
    const float c0=bg4[0],c1=bg4[1],c2=bg4[2],c3=bg4[3],c4=bg4[4],c5=bg4[5];
    if (g < K2_){
      const float* row = adjnew + ((size_t)b*K2_ + g)*K2_;
      float s = 0.f;
      #pragma unroll
      for (int i=0;i<15;i++){
        const int kk = i*16 + sub*4;
        float4 a4 = *(const float4*)(row + kk);
        float4 xq = *(const float4*)(&xv[kk]);
        s = fmaf(a4.x,xq.x,s); s = fmaf(a4.y,xq.y,s);
        s = fmaf(a4.z,xq.z,s); s = fmaf(a4.w,xq.w,s);
      }
      s += __shfl_xor(s,1); s += __shfl_xor(s,2);
      if (sub == 0){
        const float x = xv[g];
        const float z = sigf(fmaf(s,w0,c0) + fmaf(x,w1,c1));
        const float r = sigf(fmaf(s,w2,c2) + fmaf(x,w3,c3));
        const float h = fmaxf(fmaf(s,w4,c4) + fmaf(r*x,w5,c5), 0.f);
        sval[g] = h*z + x*(1.f - z);
        sidx[g] = g;
      }
    }
    if (tid >= 960 && tid < 976){
      sval[K2_ + tid - 960] = NEGINF;
      sidx[K2_ + tid - 960] = 0x7fffffff;
    }
  }
  bitonic_desc<256,1024>(sval, sidx);

  // ---- PL: gather att_x2 into fx rows 0..191 ----
  if (tid < K4_){
    const int rowi = sidx[tid];
    const float tv = tanhf(sval[tid]);
    const float* rr = &repl[(size_t)rowi*20];
    float4 r0 = *(const float4*)(rr),   r1 = *(const float4*)(rr+4);
    float4 r2 = *(const float4*)(rr+8), r3 = *(const float4*)(rr+12);
    float* o = &fx[(size_t)tid*20];
    *(float4*)(o+0)  = make_float4(tv*r0.x,tv*r0.y,tv*r0.z,tv*r0.w);
    *(float4*)(o+4)  = make_float4(tv*r1.x,tv*r1.y,tv*r1.z,tv*r1.w);
    *(float4*)(o+8)  = make_float4(tv*r2.x,tv*r2.y,tv*r2.z,tv*r2.w);
    *(float4*)(o+12) = make_float4(tv*r3.x,tv*r3.y,tv*r3.z,tv*r3.w);
  }
  __syncthreads();

  // ---- PM: att2 top-40 (one q per wave) ----
  {
    const int q = wave;
    float v[4];
    #pragma unroll
    for (int r=0;r<4;r++){
      const int idx = lane + 64*r;
      v[r] = (idx < K4_) ? fx[(size_t)idx*20 + q] : NEGINF;
    }
    wave_sort_desc<4>(v, lane);
    if (lane < 40) attl[q*120 + 80 + lane] = v[0];
  }
  __syncthreads();

  // ---- PN: MLP (weights from global/L2) + gated softmax + sum ----
  {
    const int q = tid >> 6, u = tid & 63;
    float acc = l1b[u];
    const float* wrow = l1w + (size_t)u*120;
    #pragma unroll
    for (int k4=0;k4<30;k4++){
      float4 av = *(const float4*)(&attl[q*120 + k4*4]);
      float4 wv = *(const float4*)(wrow + k4*4);
      acc = fmaf(av.x,wv.x,acc); acc = fmaf(av.y,wv.y,acc);
      acc = fmaf(av.z,wv.z,acc); acc = fmaf(av.w,wv.w,acc);
    }
    rel1[q*64 + u] = fmaxf(acc, 0.f);
  }
  __syncthreads();
  if (tid < 512){
    const int q = tid >> 5, u = tid & 31;
    float acc = l2b[u];
    const float* wrow = l2w + (size_t)u*64;
    #pragma unroll
    for (int k4=0;k4<16;k4++){
      float4 av = *(const float4*)(&rel1[q*64 + k4*4]);
      float4 wv = *(const float4*)(wrow + k4*4);
      acc = fmaf(av.x,wv.x,acc); acc = fmaf(av.y,wv.y,acc);
      acc = fmaf(av.z,wv.z,acc); acc = fmaf(av.w,wv.w,acc);
    }
    rel2[q*32 + u] = fmaxf(acc, 0.f);
  }
  __syncthreads();
  if (tid < 16){
    float acc = l3b[0];
    #pragma unroll
    for (int k=0;k<32;k++) acc = fmaf(rel2[tid*32+k], l3w[k], acc);
    const float gv = fmaf(idf[(size_t)b*16 + tid], gw[0], gb[0]);
    float mx = gv;
    mx = fmaxf(mx, __shfl_xor(mx, 1));
    mx = fmaxf(mx, __shfl_xor(mx, 2));
    mx = fmaxf(mx, __shfl_xor(mx, 4));
    mx = fmaxf(mx, __shfl_xor(mx, 8));
    const float e = __expf(gv - mx);
    float se = e;
    se += __shfl_xor(se, 1); se += __shfl_xor(se, 2);
    se += __shfl_xor(se, 4); se += __shfl_xor(se, 8);
    float val = acc * (e / se);
    val += __shfl_xor(val, 1); val += __shfl_xor(val, 2);
    val += __shfl_xor(val, 4); val += __shfl_xor(val, 8);
    if (tid == 0) outp[b] = val;
  }
}

extern "C" void kernel_launch(void* const* d_in, const int* in_sizes, int n_in,
                              void* d_out, int out_size, void* d_ws, size_t ws_size,
                              hipStream_t stream)
{
  const float* emb  = (const float*)d_in[0];
  const int*   qtok = (const int*)d_in[1];
  const int*   dtok = (const int*)d_in[2];
  const int*   dids = (const int*)d_in[3];
  const float* dadj = (const float*)d_in[4];
  const float* idf  = (const float*)d_in[5];
  const float* Wg1  = (const float*)d_in[6];
  const float* bg1  = (const float*)d_in[7];
  const float* wg2  = (const float*)d_in[8];
  const float* bg2  = (const float*)d_in[9];
  const float* Wg3  = (const float*)d_in[10];
  const float* bg3  = (const float*)d_in[11];
  const float* wg4  = (const float*)d_in[12];
  const float* bg4  = (const float*)d_in[13];
  const float* p1w  = (const float*)d_in[14];
  const float* p1b  = (const float*)d_in[15];
  const float* p2w  = (const float*)d_in[16];
  const float* p2b  = (const float*)d_in[17];
  const float* l1w  = (const float*)d_in[18];
  const float* l1b  = (const float*)d_in[19];
  const float* l2w  = (const float*)d_in[20];
  const float* l2b  = (const float*)d_in[21];
  const float* l3w  = (const float*)d_in[22];
  const float* l3b  = (const float*)d_in[23];
  const float* gw   = (const float*)d_in[24];
  const float* gb   = (const float*)d_in[25];
  float* out = (float*)d_out;

  float* adjnew = (float*)d_ws;   // B*240*240 floats = 56 MB

  const size_t lds_bytes = 32740u * 4u;   // 130960 B

  k_all<<<B_, 1024, lds_bytes, stream>>>(
      emb, qtok, dtok, dids, dadj,
      Wg1, bg1, p1w, p1b, wg2, bg2, Wg3, bg3, p2w, p2b, wg4, bg4,
      l1w, l1b, l2w, l2b, l3w, l3b, idf, gw, gb,
      adjnew, out);
}

// Round 10
// 234.315 us; speedup vs baseline: 1.2091x; 1.2091x over previous
//
#include <hip/hip_runtime.h>
#include <math.h>

#define B_   256
#define QL_  16
#define DL_  512
#define ED_  300
#define K2_  240
#define K4_  192
#define NEGINF (-3.402823466e38f)

__device__ __forceinline__ float sigf(float x){ return 1.0f/(1.0f+__expf(-x)); }

__device__ __forceinline__ float dot16(const float (&a)[16], const float* w){
  float s = 0.f;
  #pragma unroll
  for (int i=0;i<4;i++){
    float4 ww = *(const float4*)(w + 4*i);
    s = fmaf(a[4*i+0], ww.x, s);
    s = fmaf(a[4*i+1], ww.y, s);
    s = fmaf(a[4*i+2], ww.z, s);
    s = fmaf(a[4*i+3], ww.w, s);
  }
  return s;
}

// Hybrid bitonic sort of N elements (N multiple of 64, <=1024), descending by
// value, ties -> lower index. Element i lives in thread i's registers; steps
// with j<64 use wave shuffles (no barrier), j>=64 steps go through LDS.
// Exact same comparator as the LDS bitonic -> identical permutation.
template<int N>
__device__ void hybrid_sort(float* sval, int* sidx){
  const int tid = threadIdx.x;
  const bool act = (tid < N);
  __syncthreads();
  float v = NEGINF; int id = 0x7fffffff;
  if (act){ v = sval[tid]; id = sidx[tid]; }
  for (int k = 2; k <= N; k <<= 1){
    for (int j = k >> 1; j > 0; j >>= 1){
      if (j >= 64){
        if (act){ sval[tid] = v; sidx[tid] = id; }
        __syncthreads();
        if (act){
          const int p = tid ^ j;
          const float ov = sval[p]; const int oid = sidx[p];
          const bool obm = (ov > v) || (ov == v && oid < id);
          const bool lower = (tid & j) == 0;
          const bool desc = (tid & k) == 0;
          if (obm ^ (lower != desc)){ v = ov; id = oid; }
        }
        __syncthreads();
      } else {
        if (act){
          const float ov = __shfl_xor(v, j);
          const int oid = __shfl_xor(id, j);
          const bool obm = (ov > v) || (ov == v && oid < id);
          const bool lower = (tid & j) == 0;
          const bool desc = (tid & k) == 0;
          if (obm ^ (lower != desc)){ v = ov; id = oid; }
        }
      }
    }
  }
  if (act){ sval[tid] = v; sidx[tid] = id; }
  __syncthreads();
}

// in-register wave-level bitonic sort, descending, values only
template<int NREG>
__device__ __forceinline__ void wave_sort_desc(float (&v)[NREG], int lane){
  constexpr int TOT = NREG*64;
  #pragma unroll
  for (int k = 2; k <= TOT; k <<= 1){
    #pragma unroll
    for (int j = k>>1; j > 0; j >>= 1){
      if (j >= 64){
        const int jr = j >> 6;
        #pragma unroll
        for (int r = 0; r < NREG; r++){
          if ((r & jr) == 0){
            const int p = r | jr;
            const bool desc = (((r*64) & k) == 0);
            const float a = v[r], c = v[p];
            const float mx = fmaxf(a,c), mn = fminf(a,c);
            v[r] = desc ? mx : mn;
            v[p] = desc ? mn : mx;
          }
        }
      } else {
        #pragma unroll
        for (int r = 0; r < NREG; r++){
          const float ov = __shfl_xor(v[r], j);
          const bool desc = (((r*64 + lane) & k) == 0);
          const bool lower = (lane & j) == 0;
          v[r] = (lower == desc) ? fmaxf(v[r], ov) : fminf(v[r], ov);
        }
      }
    }
  }
}

// ---------------- K: the whole net for one batch item, 1024 threads --------
__global__ __launch_bounds__(1024) void k_all(
    const float* __restrict__ emb, const int* __restrict__ qtok,
    const int* __restrict__ dtok, const int* __restrict__ dids,
    const float* __restrict__ dadj,
    const float* __restrict__ Wg1, const float* __restrict__ bg1,
    const float* __restrict__ p1w, const float* __restrict__ p1b,
    const float* __restrict__ wg2, const float* __restrict__ bg2,
    const float* __restrict__ Wg3, const float* __restrict__ bg3,
    const float* __restrict__ p2w, const float* __restrict__ p2b,
    const float* __restrict__ wg4, const float* __restrict__ bg4,
    const float* __restrict__ l1w, const float* __restrict__ l1b,
    const float* __restrict__ l2w, const float* __restrict__ l2b,
    const float* __restrict__ l3w, const float* __restrict__ l3b,
    const float* __restrict__ idf, const float* __restrict__ gw,
    const float* __restrict__ gb,
    float* __restrict__ adjnew, float* __restrict__ outp)
{
  extern __shared__ float sm[];
  float* ql     = sm;              // 16*304
  float* fx     = ql + 4864;       // [512][20]
  float* repl   = fx + 10240;      // [512][20]  (fxT alias until PD)
  float* wl     = repl + 10240;    // 1536
  float* bl     = wl + 1536;       // 96
  float* pwl    = bl + 96;         // 16
  float* xv     = pwl + 16;        // 512
  float* sval   = xv + 512;        // 512
  int*   sidx   = (int*)(sval + 512);  // 512
  int*   il     = sidx + 512;      // 240
  float* attl   = (float*)(il + 240);  // 16*120
  float* rel1   = attl + 1920;     // 1024
  float* rel2   = rel1 + 1024;     // 512
  float* qinv   = rel2 + 512;      // 16
  int*   toks   = (int*)(qinv + 16);   // 512
  float* attx1T = (float*)(toks + 512);  // 16*241 (also att2T later)

  const int tid = threadIdx.x, b = blockIdx.x;
  const int wave = tid >> 6, lane = tid & 63;
  const float* abase = dadj + (size_t)dids[b]*512*512;
  float* fxT = repl;   // transposed feat [16][513], valid until PD

  // ---- PA: stage q-embeddings, doc tokens, ggnn1 weights ----
  for (int idx = tid; idx < 16*ED_; idx += 1024){
    const int q = idx / ED_, e = idx - q*ED_;
    ql[q*304+e] = emb[(size_t)qtok[(size_t)b*QL_ + q]*ED_ + e];
  }
  if (tid < 512) toks[tid] = dtok[(size_t)b*DL_ + tid];
  for (int idx = tid; idx < 1536; idx += 1024) wl[idx] = Wg1[idx];
  if (tid >= 1024-96 && tid < 1024) bl[tid-(1024-96)] = bg1[tid-(1024-96)];
  if (tid >= 512 && tid < 528) pwl[tid-512] = p1w[tid-512];
  __syncthreads();
  if (tid < 256){
    const int q = tid >> 4, s = tid & 15;
    float ss = 0.f;
    for (int e=s;e<ED_;e+=16){ const float x = ql[q*304+e]; ss = fmaf(x,x,ss); }
    ss += __shfl_xor(ss,1); ss += __shfl_xor(ss,2);
    ss += __shfl_xor(ss,4); ss += __shfl_xor(ss,8);
    if (s == 0) qinv[q] = 1.f/(sqrtf(ss)+1e-9f);
  }
  __syncthreads();

  // ---- PB: cosine feat -> fx[d][q] and fxT[q][d] (2 rows per group) ----
  {
    const int g = tid>>2, sub = tid&3;
    const float* e0p = emb + (size_t)toks[2*g+0]*ED_;
    const float* e1p = emb + (size_t)toks[2*g+1]*ED_;
    float acc[2][16];
    float ssr[2] = {0.f,0.f};
    #pragma unroll
    for (int r=0;r<2;r++)
      #pragma unroll
      for (int q=0;q<16;q++) acc[r][q] = 0.f;
    for (int i=0;i<19;i++){
      const int j = sub + 4*i;
      if (j < 75){
        const int e0 = 4*j;
        float4 d0v = *(const float4*)(e0p + e0);
        float4 d1v = *(const float4*)(e1p + e0);
        ssr[0] = fmaf(d0v.x,d0v.x, fmaf(d0v.y,d0v.y, fmaf(d0v.z,d0v.z, fmaf(d0v.w,d0v.w, ssr[0]))));
        ssr[1] = fmaf(d1v.x,d1v.x, fmaf(d1v.y,d1v.y, fmaf(d1v.z,d1v.z, fmaf(d1v.w,d1v.w, ssr[1]))));
        #pragma unroll
        for (int q=0;q<16;q++){
          float4 qv = *(const float4*)(&ql[q*304 + e0]);
          acc[0][q] = fmaf(d0v.x,qv.x, fmaf(d0v.y,qv.y, fmaf(d0v.z,qv.z, fmaf(d0v.w,qv.w, acc[0][q]))));
          acc[1][q] = fmaf(d1v.x,qv.x, fmaf(d1v.y,qv.y, fmaf(d1v.z,qv.z, fmaf(d1v.w,qv.w, acc[1][q]))));
        }
      }
    }
    #pragma unroll
    for (int r=0;r<2;r++){
      #pragma unroll
      for (int q=0;q<16;q++){
        float v = acc[r][q];
        v += __shfl_xor(v, 1);
        v += __shfl_xor(v, 2);
        acc[r][q] = v;
      }
      float sv = ssr[r];
      sv += __shfl_xor(sv, 1);
      sv += __shfl_xor(sv, 2);
      ssr[r] = sv;
    }
    if (sub < 2){
      const int d = 2*g + sub;
      const float ssd = sub ? ssr[1] : ssr[0];
      const float invd = 1.f/(sqrtf(ssd)+1e-9f);
      float vs[16];
      #pragma unroll
      for (int q=0;q<16;q++){
        const float v = sub ? acc[1][q] : acc[0][q];
        vs[q] = v * invd * qinv[q];
      }
      float* fo = &fx[(size_t)d*20];
      *(float4*)(fo+0)  = make_float4(vs[0],vs[1],vs[2],vs[3]);
      *(float4*)(fo+4)  = make_float4(vs[4],vs[5],vs[6],vs[7]);
      *(float4*)(fo+8)  = make_float4(vs[8],vs[9],vs[10],vs[11]);
      *(float4*)(fo+12) = make_float4(vs[12],vs[13],vs[14],vs[15]);
      #pragma unroll
      for (int q=0;q<16;q++) fxT[q*513 + d] = vs[q];
    }
  }
  __syncthreads();

  // ---- PC: topk0 (one q per wave; conflict-free fxT rows) ----
  {
    const int q = wave;
    float v[8];
    #pragma unroll
    for (int r=0;r<8;r++) v[r] = fxT[q*513 + lane + 64*r];
    wave_sort_desc<8>(v, lane);
    if (lane < 40) attl[q*120 + lane] = v[0];
  }
  __syncthreads();   // protect fxT (repl) from PD's writes

  // ---- PD: gemm512 + matrix gate -> repl rows, xv (2 rows per group) ----
  {
    const int g = tid>>2, sub = tid&3;
    const int mb = 2*g;
    const float* r0 = abase + (size_t)mb * 512;
    float acc[2][16];
    #pragma unroll
    for (int r=0;r<2;r++)
      #pragma unroll
      for (int q=0;q<16;q++) acc[r][q] = 0.f;
    for (int i = 0; i < 32; i++){
      const int kk = i*16 + sub*4;
      float4 a0 = *(const float4*)(r0 + kk);
      float4 a1 = *(const float4*)(r0 + 512 + kk);
      const float av[2][4] = {{a0.x,a0.y,a0.z,a0.w},{a1.x,a1.y,a1.z,a1.w}};
      #pragma unroll
      for (int c = 0; c < 4; c++){
        const float* fr = &fx[(size_t)(kk + c)*20];
        float4 q0 = *(const float4*)(fr);
        float4 q1 = *(const float4*)(fr+4);
        float4 q2 = *(const float4*)(fr+8);
        float4 q3 = *(const float4*)(fr+12);
        const float qv[16] = {q0.x,q0.y,q0.z,q0.w, q1.x,q1.y,q1.z,q1.w,
                              q2.x,q2.y,q2.z,q2.w, q3.x,q3.y,q3.z,q3.w};
        #pragma unroll
        for (int r = 0; r < 2; r++){
          const float a_ = av[r][c];
          #pragma unroll
          for (int q = 0; q < 16; q++)
            acc[r][q] = fmaf(a_, qv[q], acc[r][q]);
        }
      }
    }
    #pragma unroll
    for (int r=0;r<2;r++)
      #pragma unroll
      for (int q=0;q<16;q++){
        float v = acc[r][q];
        v += __shfl_xor(v, 1);
        v += __shfl_xor(v, 2);
        acc[r][q] = v;
      }
    if (sub < 2){
      const int m = mb + sub;
      float a[16], x[16];
      #pragma unroll
      for (int q=0;q<16;q++)
        a[q] = sub ? acc[1][q] : acc[0][q];
      {
        const float* xr = &fx[(size_t)m*20];
        float4 x0 = *(const float4*)(xr),   x1 = *(const float4*)(xr+4);
        float4 x2v = *(const float4*)(xr+8), x3 = *(const float4*)(xr+12);
        x[0]=x0.x; x[1]=x0.y; x[2]=x0.z; x[3]=x0.w;
        x[4]=x1.x; x[5]=x1.y; x[6]=x1.z; x[7]=x1.w;
        x[8]=x2v.x; x[9]=x2v.y; x[10]=x2v.z; x[11]=x2v.w;
        x[12]=x3.x; x[13]=x3.y; x[14]=x3.z; x[15]=x3.w;
      }
      float z[16], rr[16];
      #pragma unroll
      for (int q=0;q<16;q++){
        const float s0 = bl[q] + bl[16+q]
                       + dot16(a, &wl[q*16]) + dot16(x, &wl[256 + q*16]);
        z[q] = sigf(s0);
        const float s1 = bl[32+q] + bl[48+q]
                       + dot16(a, &wl[512 + q*16]) + dot16(x, &wl[768 + q*16]);
        rr[q] = sigf(s1);
      }
      float rx[16];
      #pragma unroll
      for (int q=0;q<16;q++) rx[q] = rr[q]*x[q];
      float out[16]; float xp = 0.f;
      #pragma unroll
      for (int q=0;q<16;q++){
        const float s = bl[64+q] + bl[80+q]
                      + dot16(a, &wl[1024 + q*16]) + dot16(rx, &wl[1280 + q*16]);
        const float h = fmaxf(s, 0.f);
        const float o = h*z[q] + x[q]*(1.f - z[q]);
        out[q] = o;
        xp = fmaf(o, pwl[q], xp);
      }
      float* rp = &repl[(size_t)m*20];
      *(float4*)(rp+0)  = make_float4(out[0],out[1],out[2],out[3]);
      *(float4*)(rp+4)  = make_float4(out[4],out[5],out[6],out[7]);
      *(float4*)(rp+8)  = make_float4(out[8],out[9],out[10],out[11]);
      *(float4*)(rp+12) = make_float4(out[12],out[13],out[14],out[15]);
      xv[m] = xp + p1b[0];
    }
  }
  __syncthreads();

  // ---- PE: score1 = gate(adj@x2, x2), all 16 waves (adj L2/L3-hot) ----
  {
    const int g = tid >> 2, sub = tid & 3;
    const float w0=wg2[0],w1=wg2[1],w2=wg2[2],w3=wg2[3],w4=wg2[4],w5=wg2[5];
    const float c0=bg2[0],c1=bg2[1],c2=bg2[2],c3=bg2[3],c4=bg2[4],c5=bg2[5];
    #pragma unroll
    for (int pp=0; pp<2; pp++){
      const int m = pp*256 + g;
      const float* row = abase + (size_t)m*512;
      float s = 0.f;
      #pragma unroll
      for (int ii=0; ii<8; ii++){
        const int k0 = ii*64 + sub*4;
        float4 a0 = *(const float4*)(row + k0);
        float4 a1 = *(const float4*)(row + k0 + 16);
        float4 a2 = *(const float4*)(row + k0 + 32);
        float4 a3 = *(const float4*)(row + k0 + 48);
        float4 x0 = *(const float4*)(&xv[k0]);
        float4 x1 = *(const float4*)(&xv[k0+16]);
        float4 x2v = *(const float4*)(&xv[k0+32]);
        float4 x3 = *(const float4*)(&xv[k0+48]);
        s = fmaf(a0.x,x0.x,s); s = fmaf(a0.y,x0.y,s);
        s = fmaf(a0.z,x0.z,s); s = fmaf(a0.w,x0.w,s);
        s = fmaf(a1.x,x1.x,s); s = fmaf(a1.y,x1.y,s);
        s = fmaf(a1.z,x1.z,s); s = fmaf(a1.w,x1.w,s);
        s = fmaf(a2.x,x2v.x,s); s = fmaf(a2.y,x2v.y,s);
        s = fmaf(a2.z,x2v.z,s); s = fmaf(a2.w,x2v.w,s);
        s = fmaf(a3.x,x3.x,s); s = fmaf(a3.y,x3.y,s);
        s = fmaf(a3.z,x3.z,s); s = fmaf(a3.w,x3.w,s);
      }
      s += __shfl_xor(s,1); s += __shfl_xor(s,2);
      if (sub == 0){
        const float x = xv[m];
        const float z = sigf(fmaf(s,w0,c0) + fmaf(x,w1,c1));
        const float r = sigf(fmaf(s,w2,c2) + fmaf(x,w3,c3));
        const float h = fmaxf(fmaf(s,w4,c4) + fmaf(r*x,w5,c5), 0.f);
        sval[m] = h*z + x*(1.f - z);
        sidx[m] = m;
      }
    }
  }
  hybrid_sort<512>(sval, sidx);

  // ---- PG: gather att_x1 into fx rows 0..239 + attx1T, record il ----
  if (tid < K2_){
    const int rowi = sidx[tid];
    il[tid] = rowi;
    const float tv = tanhf(sval[tid]);
    const float* rr = &repl[(size_t)rowi*20];
    float4 r0 = *(const float4*)(rr),   r1 = *(const float4*)(rr+4);
    float4 r2 = *(const float4*)(rr+8), r3 = *(const float4*)(rr+12);
    const float vv[16] = {tv*r0.x,tv*r0.y,tv*r0.z,tv*r0.w,
                          tv*r1.x,tv*r1.y,tv*r1.z,tv*r1.w,
                          tv*r2.x,tv*r2.y,tv*r2.z,tv*r2.w,
                          tv*r3.x,tv*r3.y,tv*r3.z,tv*r3.w};
    float* o = &fx[(size_t)tid*20];
    *(float4*)(o+0)  = make_float4(vv[0],vv[1],vv[2],vv[3]);
    *(float4*)(o+4)  = make_float4(vv[4],vv[5],vv[6],vv[7]);
    *(float4*)(o+8)  = make_float4(vv[8],vv[9],vv[10],vv[11]);
    *(float4*)(o+12) = make_float4(vv[12],vv[13],vv[14],vv[15]);
    #pragma unroll
    for (int q=0;q<16;q++) attx1T[q*241 + tid] = vv[q];
  }
  __syncthreads();

  // ---- PH: waves 0-11 subadj gather || waves 12-15 Wg3 staging + att1 ----
  if (wave < 12){
    int jc[4];
    #pragma unroll
    for (int c=0;c<4;c++){
      const int j = lane + 64*c;
      jc[c] = (j < K2_) ? il[j] : 0;
    }
    #pragma unroll
    for (int p=0;p<20;p++){
      const int r = wave*20 + p;
      const float* row = abase + (size_t)il[r]*512;
      float* orow = adjnew + ((size_t)b*K2_ + r)*K2_;
      #pragma unroll
      for (int c=0;c<4;c++){
        const int j = lane + 64*c;
        if (j < K2_) orow[j] = row[jc[c]];
      }
    }
  } else {
    const int t4 = tid - 768;
    for (int idx = t4; idx < 1536; idx += 256) wl[idx] = Wg3[idx];
    if (t4 < 96) bl[t4] = bg3[t4];
    if (t4 < 16) pwl[t4] = p2w[t4];
    #pragma unroll
    for (int t=0;t<4;t++){
      const int q = (wave-12)*4 + t;
      float v[4];
      #pragma unroll
      for (int r=0;r<4;r++){
        const int idx = lane + 64*r;
        v[r] = (idx < K2_) ? attx1T[q*241 + idx] : NEGINF;
      }
      wave_sort_desc<4>(v, lane);
      if (lane < 40) attl[q*120 + 40 + lane] = v[0];
    }
  }
  __syncthreads();

  // ---- PI: gemm240 + matrix gate -> repl, xv(=x4) ----
  {
    const int g = tid >> 2, sub = tid & 3;
    if (g < K2_){
      const int m = g;
      const float* r0 = adjnew + ((size_t)b*K2_ + m)*K2_;
      float acc[16];
      #pragma unroll
      for (int q=0;q<16;q++) acc[q] = 0.f;
      for (int i=0;i<15;i++){
        const int kk = i*16 + sub*4;
        float4 a4 = *(const float4*)(r0 + kk);
        const float av[4] = {a4.x, a4.y, a4.z, a4.w};
        #pragma unroll
        for (int c=0;c<4;c++){
          const float* fr = &fx[(size_t)(kk + c)*20];
          float4 q0 = *(const float4*)(fr);
          float4 q1 = *(const float4*)(fr+4);
          float4 q2 = *(const float4*)(fr+8);
          float4 q3 = *(const float4*)(fr+12);
          const float qv[16] = {q0.x,q0.y,q0.z,q0.w, q1.x,q1.y,q1.z,q1.w,
                                q2.x,q2.y,q2.z,q2.w, q3.x,q3.y,q3.z,q3.w};
          #pragma unroll
          for (int q=0;q<16;q++)
            acc[q] = fmaf(av[c], qv[q], acc[q]);
        }
      }
      #pragma unroll
      for (int q=0;q<16;q++){
        float v = acc[q];
        v += __shfl_xor(v, 1);
        v += __shfl_xor(v, 2);
        acc[q] = v;
      }
      float x[16];
      {
        const float* xr = &fx[(size_t)m*20];
        float4 x0 = *(const float4*)(xr),   x1 = *(const float4*)(xr+4);
        float4 x2v = *(const float4*)(xr+8), x3 = *(const float4*)(xr+12);
        x[0]=x0.x; x[1]=x0.y; x[2]=x0.z; x[3]=x0.w;
        x[4]=x1.x; x[5]=x1.y; x[6]=x1.z; x[7]=x1.w;
        x[8]=x2v.x; x[9]=x2v.y; x[10]=x2v.z; x[11]=x2v.w;
        x[12]=x3.x; x[13]=x3.y; x[14]=x3.z; x[15]=x3.w;
      }
      float rx[16];
      #pragma unroll
      for (int q=0;q<16;q++){
        const float s1 = bl[32+q] + bl[48+q]
                       + dot16(acc, &wl[512 + q*16]) + dot16(x, &wl[768 + q*16]);
        rx[q] = sigf(s1) * x[q];
      }
      float xp = 0.f;
      #pragma unroll
      for (int j=0;j<4;j++){
        const int q = sub*4 + j;
        const float s0 = bl[q] + bl[16+q]
                       + dot16(acc, &wl[q*16]) + dot16(x, &wl[256 + q*16]);
        const float z = sigf(s0);
        const float s = bl[64+q] + bl[80+q]
                      + dot16(acc, &wl[1024 + q*16]) + dot16(rx, &wl[1280 + q*16]);
        const float h = fmaxf(s, 0.f);
        const float o = h*z + x[q]*(1.f - z);
        repl[(size_t)m*20 + q] = o;
        xp = fmaf(o, pwl[q], xp);
      }
      xp += __shfl_xor(xp,1); xp += __shfl_xor(xp,2);
      if (sub == 0) xv[m] = xp + p2b[0];
    }
  }
  __syncthreads();

  // ---- PJ: score2 ----
  {
    const int g = tid >> 2, sub = tid & 3;
    const float w0=wg4[0],w1=wg4[1],w2=wg4[2],w3=wg4[3],w4=wg4[4],w5=wg4[5];
    const float c0=bg4[0],c1=bg4[1],c2=bg4[2],c3=bg4[3],c4=bg4[4],c5=bg4[5];
    if (g < K2_){
      const float* row = adjnew + ((size_t)b*K2_ + g)*K2_;
      float s = 0.f;
      #pragma unroll
      for (int i=0;i<15;i++){
        const int kk = i*16 + sub*4;
        float4 a4 = *(const float4*)(row + kk);
        float4 xq = *(const float4*)(&xv[kk]);
        s = fmaf(a4.x,xq.x,s); s = fmaf(a4.y,xq.y,s);
        s = fmaf(a4.z,xq.z,s); s = fmaf(a4.w,xq.w,s);
      }
      s += __shfl_xor(s,1); s += __shfl_xor(s,2);
      if (sub == 0){
        const float x = xv[g];
        const float z = sigf(fmaf(s,w0,c0) + fmaf(x,w1,c1));
        const float r = sigf(fmaf(s,w2,c2) + fmaf(x,w3,c3));
        const float h = fmaxf(fmaf(s,w4,c4) + fmaf(r*x,w5,c5), 0.f);
        sval[g] = h*z + x*(1.f - z);
        sidx[g] = g;
      }
    }
    if (tid >= 960 && tid < 976){
      sval[K2_ + tid - 960] = NEGINF;
      sidx[K2_ + tid - 960] = 0x7fffffff;
    }
  }
  hybrid_sort<256>(sval, sidx);

  // ---- PL: gather att_x2 into fx rows 0..191 + attx2T (reuse attx1T) ----
  if (tid < K4_){
    const int rowi = sidx[tid];
    const float tv = tanhf(sval[tid]);
    const float* rr = &repl[(size_t)rowi*20];
    float4 r0 = *(const float4*)(rr),   r1 = *(const float4*)(rr+4);
    float4 r2 = *(const float4*)(rr+8), r3 = *(const float4*)(rr+12);
    const float vv[16] = {tv*r0.x,tv*r0.y,tv*r0.z,tv*r0.w,
                          tv*r1.x,tv*r1.y,tv*r1.z,tv*r1.w,
                          tv*r2.x,tv*r2.y,tv*r2.z,tv*r2.w,
                          tv*r3.x,tv*r3.y,tv*r3.z,tv*r3.w};
    #pragma unroll
    for (int q=0;q<16;q++) attx1T[q*241 + tid] = vv[q];
  }
  __syncthreads();

  // ---- PM: att2 top-40 (one q per wave) ----
  {
    const int q = wave;
    float v[4];
    #pragma unroll
    for (int r=0;r<4;r++){
      const int idx = lane + 64*r;
      v[r] = (idx < K4_) ? attx1T[q*241 + idx] : NEGINF;
    }
    wave_sort_desc<4>(v, lane);
    if (lane < 40) attl[q*120 + 80 + lane] = v[0];
  }
  __syncthreads();

  // ---- PN: MLP (weights from global/L2) + gated softmax + sum ----
  {
    const int q = tid >> 6, u = tid & 63;
    float acc = l1b[u];
    const float* wrow = l1w + (size_t)u*120;
    #pragma unroll
    for (int k4=0;k4<30;k4++){
      float4 av = *(const float4*)(&attl[q*120 + k4*4]);
      float4 wv = *(const float4*)(wrow + k4*4);
      acc = fmaf(av.x,wv.x,acc); acc = fmaf(av.y,wv.y,acc);
      acc = fmaf(av.z,wv.z,acc); acc = fmaf(av.w,wv.w,acc);
    }
    rel1[q*64 + u] = fmaxf(acc, 0.f);
  }
  __syncthreads();
  if (tid < 512){
    const int q = tid >> 5, u = tid & 31;
    float acc = l2b[u];
    const float* wrow = l2w + (size_t)u*64;
    #pragma unroll
    for (int k4=0;k4<16;k4++){
      float4 av = *(const float4*)(&rel1[q*64 + k4*4]);
      float4 wv = *(const float4*)(wrow + k4*4);
      acc = fmaf(av.x,wv.x,acc); acc = fmaf(av.y,wv.y,acc);
      acc = fmaf(av.z,wv.z,acc); acc = fmaf(av.w,wv.w,acc);
    }
    rel2[q*32 + u] = fmaxf(acc, 0.f);
  }
  __syncthreads();
  if (tid < 16){
    float acc = l3b[0];
    #pragma unroll
    for (int k=0;k<32;k++) acc = fmaf(rel2[tid*32+k], l3w[k], acc);
    const float gv = fmaf(idf[(size_t)b*16 + tid], gw[0], gb[0]);
    float mx = gv;
    mx = fmaxf(mx, __shfl_xor(mx, 1));
    mx = fmaxf(mx, __shfl_xor(mx, 2));
    mx = fmaxf(mx, __shfl_xor(mx, 4));
    mx = fmaxf(mx, __shfl_xor(mx, 8));
    const float e = __expf(gv - mx);
    float se = e;
    se += __shfl_xor(se, 1); se += __shfl_xor(se, 2);
    se += __shfl_xor(se, 4); se += __shfl_xor(se, 8);
    float val = acc * (e / se);
    val += __shfl_xor(val, 1); val += __shfl_xor(val, 2);
    val += __shfl_xor(val, 4); val += __shfl_xor(val, 8);
    if (tid == 0) outp[b] = val;
  }
}

extern "C" void kernel_launch(void* const* d_in, const int* in_sizes, int n_in,
                              void* d_out, int out_size, void* d_ws, size_t ws_size,
                              hipStream_t stream)
{
  const float* emb  = (const float*)d_in[0];
  const int*   qtok = (const int*)d_in[1];
  const int*   dtok = (const int*)d_in[2];
  const int*   dids = (const int*)d_in[3];
  const float* dadj = (const float*)d_in[4];
  const float* idf  = (const float*)d_in[5];
  const float* Wg1  = (const float*)d_in[6];
  const float* bg1  = (const float*)d_in[7];
  const float* wg2  = (const float*)d_in[8];
  const float* bg2  = (const float*)d_in[9];
  const float* Wg3  = (const float*)d_in[10];
  const float* bg3  = (const float*)d_in[11];
  const float* wg4  = (const float*)d_in[12];
  const float* bg4  = (const float*)d_in[13];
  const float* p1w  = (const float*)d_in[14];
  const float* p1b  = (const float*)d_in[15];
  const float* p2w  = (const float*)d_in[16];
  const float* p2b  = (const float*)d_in[17];
  const float* l1w  = (const float*)d_in[18];
  const float* l1b  = (const float*)d_in[19];
  const float* l2w  = (const float*)d_in[20];
  const float* l2b  = (const float*)d_in[21];
  const float* l3w  = (const float*)d_in[22];
  const float* l3b  = (const float*)d_in[23];
  const float* gw   = (const float*)d_in[24];
  const float* gb   = (const float*)d_in[25];
  float* out = (float*)d_out;

  float* adjnew = (float*)d_ws;   // B*240*240 floats = 56 MB

  const size_t lds_bytes = 36608u * 4u;   // 146432 B

  k_all<<<B_, 1024, lds_bytes, stream>>>(
      emb, qtok, dtok, dids, dadj,
      Wg1, bg1, p1w, p1b, wg2, bg2, Wg3, bg3, p2w, p2b, wg4, bg4,
      l1w, l1b, l2w, l2b, l3w, l3b, idf, gw, gb,
      adjnew, out);
}

// Round 11
// 216.336 us; speedup vs baseline: 1.3096x; 1.0831x over previous
//
#include <hip/hip_runtime.h>
#include <math.h>

#define B_   256
#define QL_  16
#define DL_  512
#define ED_  300
#define K2_  240
#define K4_  192
#define NEGINF (-3.402823466e38f)

__device__ __forceinline__ float sigf(float x){ return 1.0f/(1.0f+__expf(-x)); }

__device__ __forceinline__ float dot16(const float (&a)[16], const float* w){
  float s = 0.f;
  #pragma unroll
  for (int i=0;i<4;i++){
    float4 ww = *(const float4*)(w + 4*i);
    s = fmaf(a[4*i+0], ww.x, s);
    s = fmaf(a[4*i+1], ww.y, s);
    s = fmaf(a[4*i+2], ww.z, s);
    s = fmaf(a[4*i+3], ww.w, s);
  }
  return s;
}

// Hybrid bitonic sort: element i in thread i's regs; j<64 steps via shuffles,
// j>=64 via LDS. Descending, ties -> lower index. Identical permutation to
// the LDS bitonic.
template<int N>
__device__ void hybrid_sort(float* sval, int* sidx){
  const int tid = threadIdx.x;
  const bool act = (tid < N);
  __syncthreads();
  float v = NEGINF; int id = 0x7fffffff;
  if (act){ v = sval[tid]; id = sidx[tid]; }
  for (int k = 2; k <= N; k <<= 1){
    for (int j = k >> 1; j > 0; j >>= 1){
      if (j >= 64){
        if (act){ sval[tid] = v; sidx[tid] = id; }
        __syncthreads();
        if (act){
          const int p = tid ^ j;
          const float ov = sval[p]; const int oid = sidx[p];
          const bool obm = (ov > v) || (ov == v && oid < id);
          const bool lower = (tid & j) == 0;
          const bool desc = (tid & k) == 0;
          if (obm ^ (lower != desc)){ v = ov; id = oid; }
        }
        __syncthreads();
      } else {
        if (act){
          const float ov = __shfl_xor(v, j);
          const int oid = __shfl_xor(id, j);
          const bool obm = (ov > v) || (ov == v && oid < id);
          const bool lower = (tid & j) == 0;
          const bool desc = (tid & k) == 0;
          if (obm ^ (lower != desc)){ v = ov; id = oid; }
        }
      }
    }
  }
  if (act){ sval[tid] = v; sidx[tid] = id; }
  __syncthreads();
}

// in-register wave-level bitonic sort, descending, values only
template<int NREG>
__device__ __forceinline__ void wave_sort_desc(float (&v)[NREG], int lane){
  constexpr int TOT = NREG*64;
  #pragma unroll
  for (int k = 2; k <= TOT; k <<= 1){
    #pragma unroll
    for (int j = k>>1; j > 0; j >>= 1){
      if (j >= 64){
        const int jr = j >> 6;
        #pragma unroll
        for (int r = 0; r < NREG; r++){
          if ((r & jr) == 0){
            const int p = r | jr;
            const bool desc = (((r*64) & k) == 0);
            const float a = v[r], c = v[p];
            const float mx = fmaxf(a,c), mn = fminf(a,c);
            v[r] = desc ? mx : mn;
            v[p] = desc ? mn : mx;
          }
        }
      } else {
        #pragma unroll
        for (int r = 0; r < NREG; r++){
          const float ov = __shfl_xor(v[r], j);
          const bool desc = (((r*64 + lane) & k) == 0);
          const bool lower = (lane & j) == 0;
          v[r] = (lower == desc) ? fmaxf(v[r], ov) : fminf(v[r], ov);
        }
      }
    }
  }
}

// ---------------- K: whole net per batch item; 1024 thr, 1 block/CU --------
// __launch_bounds__(1024,4): 4 waves/EU min -> 128 VGPR cap (we run exactly
// 16 waves/CU because LDS=146KB forces 1 block/CU; the default 64-VGPR cap
// for 2 blocks/CU bought nothing and starved ILP / spilled R9's acc[4][16]).
__global__ __launch_bounds__(1024, 4) void k_all(
    const float* __restrict__ emb, const int* __restrict__ qtok,
    const int* __restrict__ dtok, const int* __restrict__ dids,
    const float* __restrict__ dadj,
    const float* __restrict__ Wg1, const float* __restrict__ bg1,
    const float* __restrict__ p1w, const float* __restrict__ p1b,
    const float* __restrict__ wg2, const float* __restrict__ bg2,
    const float* __restrict__ Wg3, const float* __restrict__ bg3,
    const float* __restrict__ p2w, const float* __restrict__ p2b,
    const float* __restrict__ wg4, const float* __restrict__ bg4,
    const float* __restrict__ l1w, const float* __restrict__ l1b,
    const float* __restrict__ l2w, const float* __restrict__ l2b,
    const float* __restrict__ l3w, const float* __restrict__ l3b,
    const float* __restrict__ idf, const float* __restrict__ gw,
    const float* __restrict__ gb,
    float* __restrict__ adjnew, float* __restrict__ outp)
{
  extern __shared__ float sm[];
  float* ql     = sm;              // 16*304
  float* fx     = ql + 4864;       // [512][20]
  float* repl   = fx + 10240;      // [512][20]
  float* wl     = repl + 10240;    // 1536
  float* bl     = wl + 1536;       // 96
  float* pwl    = bl + 96;         // 16
  float* xv     = pwl + 16;        // 512
  float* sval   = xv + 512;        // 512
  int*   sidx   = (int*)(sval + 512);  // 512
  int*   il     = sidx + 512;      // 240
  float* attl   = (float*)(il + 240);  // 16*120
  float* rel1   = attl + 1920;     // 1024
  float* rel2   = rel1 + 1024;     // 512
  float* qinv   = rel2 + 512;      // 16
  int*   toks   = (int*)(qinv + 16);   // 512
  float* attx1T = (float*)(toks + 512);  // 16*241 (also att2T later)

  const int tid = threadIdx.x, b = blockIdx.x;
  const int wave = tid >> 6, lane = tid & 63;
  const float* abase = dadj + (size_t)dids[b]*512*512;

  // ---- PA: stage q-embeddings, doc tokens, ggnn1 weights ----
  for (int idx = tid; idx < 16*ED_; idx += 1024){
    const int q = idx / ED_, e = idx - q*ED_;
    ql[q*304+e] = emb[(size_t)qtok[(size_t)b*QL_ + q]*ED_ + e];
  }
  if (tid < 512) toks[tid] = dtok[(size_t)b*DL_ + tid];
  for (int idx = tid; idx < 1536; idx += 1024) wl[idx] = Wg1[idx];
  if (tid >= 1024-96 && tid < 1024) bl[tid-(1024-96)] = bg1[tid-(1024-96)];
  if (tid >= 512 && tid < 528) pwl[tid-512] = p1w[tid-512];
  __syncthreads();
  if (tid < 256){
    const int q = tid >> 4, s = tid & 15;
    float ss = 0.f;
    for (int e=s;e<ED_;e+=16){ const float x = ql[q*304+e]; ss = fmaf(x,x,ss); }
    ss += __shfl_xor(ss,1); ss += __shfl_xor(ss,2);
    ss += __shfl_xor(ss,4); ss += __shfl_xor(ss,8);
    if (s == 0) qinv[q] = 1.f/(sqrtf(ss)+1e-9f);
  }
  __syncthreads();

  // ---- PB: cosine feat -> fx[d][q] (2 rows per 4-lane group) ----
  {
    const int g = tid>>2, sub = tid&3;
    const float* e0p = emb + (size_t)toks[2*g+0]*ED_;
    const float* e1p = emb + (size_t)toks[2*g+1]*ED_;
    float acc[2][16];
    float ssr[2] = {0.f,0.f};
    #pragma unroll
    for (int r=0;r<2;r++)
      #pragma unroll
      for (int q=0;q<16;q++) acc[r][q] = 0.f;
    for (int i=0;i<19;i++){
      const int j = sub + 4*i;
      if (j < 75){
        const int e0 = 4*j;
        float4 d0v = *(const float4*)(e0p + e0);
        float4 d1v = *(const float4*)(e1p + e0);
        ssr[0] = fmaf(d0v.x,d0v.x, fmaf(d0v.y,d0v.y, fmaf(d0v.z,d0v.z, fmaf(d0v.w,d0v.w, ssr[0]))));
        ssr[1] = fmaf(d1v.x,d1v.x, fmaf(d1v.y,d1v.y, fmaf(d1v.z,d1v.z, fmaf(d1v.w,d1v.w, ssr[1]))));
        #pragma unroll
        for (int q=0;q<16;q++){
          float4 qv = *(const float4*)(&ql[q*304 + e0]);
          acc[0][q] = fmaf(d0v.x,qv.x, fmaf(d0v.y,qv.y, fmaf(d0v.z,qv.z, fmaf(d0v.w,qv.w, acc[0][q]))));
          acc[1][q] = fmaf(d1v.x,qv.x, fmaf(d1v.y,qv.y, fmaf(d1v.z,qv.z, fmaf(d1v.w,qv.w, acc[1][q]))));
        }
      }
    }
    #pragma unroll
    for (int r=0;r<2;r++){
      #pragma unroll
      for (int q=0;q<16;q++){
        float v = acc[r][q];
        v += __shfl_xor(v, 1);
        v += __shfl_xor(v, 2);
        acc[r][q] = v;
      }
      float sv = ssr[r];
      sv += __shfl_xor(sv, 1);
      sv += __shfl_xor(sv, 2);
      ssr[r] = sv;
    }
    if (sub < 2){
      const int d = 2*g + sub;
      const float ssd = sub ? ssr[1] : ssr[0];
      const float invd = 1.f/(sqrtf(ssd)+1e-9f);
      float vs[16];
      #pragma unroll
      for (int q=0;q<16;q++){
        const float v = sub ? acc[1][q] : acc[0][q];
        vs[q] = v * invd * qinv[q];
      }
      float* fo = &fx[(size_t)d*20];
      *(float4*)(fo+0)  = make_float4(vs[0],vs[1],vs[2],vs[3]);
      *(float4*)(fo+4)  = make_float4(vs[4],vs[5],vs[6],vs[7]);
      *(float4*)(fo+8)  = make_float4(vs[8],vs[9],vs[10],vs[11]);
      *(float4*)(fo+12) = make_float4(vs[12],vs[13],vs[14],vs[15]);
    }
  }
  __syncthreads();

  // ---- PD: waves 0-7 gemm512+gate (4 rows/group, 16:1 FMA:LDS) ||
  //          waves 8-15 topk0 (2 q/wave, fx-column reads, overlapped) ----
  if (wave < 8){
    const int g = tid >> 2, sub = tid & 3;    // g in [0,128)
    const int mb = 4*g;
    const float* r0 = abase + (size_t)mb * 512;
    float acc[4][16];
    #pragma unroll
    for (int r=0;r<4;r++)
      #pragma unroll
      for (int q=0;q<16;q++) acc[r][q] = 0.f;
    for (int i = 0; i < 32; i++){
      const int kk = i*16 + sub*4;
      float4 a0 = *(const float4*)(r0 + kk);
      float4 a1 = *(const float4*)(r0 + 512 + kk);
      float4 a2 = *(const float4*)(r0 + 2*512 + kk);
      float4 a3 = *(const float4*)(r0 + 3*512 + kk);
      const float av[4][4] = {{a0.x,a0.y,a0.z,a0.w},{a1.x,a1.y,a1.z,a1.w},
                              {a2.x,a2.y,a2.z,a2.w},{a3.x,a3.y,a3.z,a3.w}};
      #pragma unroll
      for (int c = 0; c < 4; c++){
        const float* fr = &fx[(size_t)(kk + c)*20];
        float4 q0 = *(const float4*)(fr);
        float4 q1 = *(const float4*)(fr+4);
        float4 q2 = *(const float4*)(fr+8);
        float4 q3 = *(const float4*)(fr+12);
        const float qv[16] = {q0.x,q0.y,q0.z,q0.w, q1.x,q1.y,q1.z,q1.w,
                              q2.x,q2.y,q2.z,q2.w, q3.x,q3.y,q3.z,q3.w};
        #pragma unroll
        for (int r = 0; r < 4; r++){
          const float a_ = av[r][c];
          #pragma unroll
          for (int q = 0; q < 16; q++)
            acc[r][q] = fmaf(a_, qv[q], acc[r][q]);
        }
      }
    }
    #pragma unroll
    for (int r=0;r<4;r++)
      #pragma unroll
      for (int q=0;q<16;q++){
        float v = acc[r][q];
        v += __shfl_xor(v, 1);
        v += __shfl_xor(v, 2);
        acc[r][q] = v;
      }
    const int m = mb + sub;
    float a[16], x[16];
    #pragma unroll
    for (int q=0;q<16;q++)
      a[q] = (sub==0)?acc[0][q]:(sub==1)?acc[1][q]:(sub==2)?acc[2][q]:acc[3][q];
    {
      const float* xr = &fx[(size_t)m*20];
      float4 x0 = *(const float4*)(xr),   x1 = *(const float4*)(xr+4);
      float4 x2v = *(const float4*)(xr+8), x3 = *(const float4*)(xr+12);
      x[0]=x0.x; x[1]=x0.y; x[2]=x0.z; x[3]=x0.w;
      x[4]=x1.x; x[5]=x1.y; x[6]=x1.z; x[7]=x1.w;
      x[8]=x2v.x; x[9]=x2v.y; x[10]=x2v.z; x[11]=x2v.w;
      x[12]=x3.x; x[13]=x3.y; x[14]=x3.z; x[15]=x3.w;
    }
    float z[16], rr[16];
    #pragma unroll
    for (int q=0;q<16;q++){
      const float s0 = bl[q] + bl[16+q]
                     + dot16(a, &wl[q*16]) + dot16(x, &wl[256 + q*16]);
      z[q] = sigf(s0);
      const float s1 = bl[32+q] + bl[48+q]
                     + dot16(a, &wl[512 + q*16]) + dot16(x, &wl[768 + q*16]);
      rr[q] = sigf(s1);
    }
    float rx[16];
    #pragma unroll
    for (int q=0;q<16;q++) rx[q] = rr[q]*x[q];
    float out[16]; float xp = 0.f;
    #pragma unroll
    for (int q=0;q<16;q++){
      const float s = bl[64+q] + bl[80+q]
                    + dot16(a, &wl[1024 + q*16]) + dot16(rx, &wl[1280 + q*16]);
      const float h = fmaxf(s, 0.f);
      const float o = h*z[q] + x[q]*(1.f - z[q]);
      out[q] = o;
      xp = fmaf(o, pwl[q], xp);
    }
    float* rp = &repl[(size_t)m*20];
    *(float4*)(rp+0)  = make_float4(out[0],out[1],out[2],out[3]);
    *(float4*)(rp+4)  = make_float4(out[4],out[5],out[6],out[7]);
    *(float4*)(rp+8)  = make_float4(out[8],out[9],out[10],out[11]);
    *(float4*)(rp+12) = make_float4(out[12],out[13],out[14],out[15]);
    xv[m] = xp + p1b[0];
  } else {
    #pragma unroll
    for (int t=0;t<2;t++){
      const int q = (wave-8)*2 + t;
      float v[8];
      #pragma unroll
      for (int r=0;r<8;r++) v[r] = fx[(size_t)(lane + 64*r)*20 + q];
      wave_sort_desc<8>(v, lane);
      if (lane < 40) attl[q*120 + lane] = v[0];
    }
  }
  __syncthreads();

  // ---- PE: score1 = gate(adj@x2, x2), all 16 waves (adj L2/L3-hot) ----
  {
    const int g = tid >> 2, sub = tid & 3;
    const float w0=wg2[0],w1=wg2[1],w2=wg2[2],w3=wg2[3],w4=wg2[4],w5=wg2[5];
    const float c0=bg2[0],c1=bg2[1],c2=bg2[2],c3=bg2[3],c4=bg2[4],c5=bg2[5];
    #pragma unroll
    for (int pp=0; pp<2; pp++){
      const int m = pp*256 + g;
      const float* row = abase + (size_t)m*512;
      float s = 0.f;
      #pragma unroll
      for (int ii=0; ii<8; ii++){
        const int k0 = ii*64 + sub*4;
        float4 a0 = *(const float4*)(row + k0);
        float4 a1 = *(const float4*)(row + k0 + 16);
        float4 a2 = *(const float4*)(row + k0 + 32);
        float4 a3 = *(const float4*)(row + k0 + 48);
        float4 x0 = *(const float4*)(&xv[k0]);
        float4 x1 = *(const float4*)(&xv[k0+16]);
        float4 x2v = *(const float4*)(&xv[k0+32]);
        float4 x3 = *(const float4*)(&xv[k0+48]);
        s = fmaf(a0.x,x0.x,s); s = fmaf(a0.y,x0.y,s);
        s = fmaf(a0.z,x0.z,s); s = fmaf(a0.w,x0.w,s);
        s = fmaf(a1.x,x1.x,s); s = fmaf(a1.y,x1.y,s);
        s = fmaf(a1.z,x1.z,s); s = fmaf(a1.w,x1.w,s);
        s = fmaf(a2.x,x2v.x,s); s = fmaf(a2.y,x2v.y,s);
        s = fmaf(a2.z,x2v.z,s); s = fmaf(a2.w,x2v.w,s);
        s = fmaf(a3.x,x3.x,s); s = fmaf(a3.y,x3.y,s);
        s = fmaf(a3.z,x3.z,s); s = fmaf(a3.w,x3.w,s);
      }
      s += __shfl_xor(s,1); s += __shfl_xor(s,2);
      if (sub == 0){
        const float x = xv[m];
        const float z = sigf(fmaf(s,w0,c0) + fmaf(x,w1,c1));
        const float r = sigf(fmaf(s,w2,c2) + fmaf(x,w3,c3));
        const float h = fmaxf(fmaf(s,w4,c4) + fmaf(r*x,w5,c5), 0.f);
        sval[m] = h*z + x*(1.f - z);
        sidx[m] = m;
      }
    }
  }
  hybrid_sort<512>(sval, sidx);

  // ---- PG: gather att_x1 into fx rows 0..239 + attx1T, record il ----
  if (tid < K2_){
    const int rowi = sidx[tid];
    il[tid] = rowi;
    const float tv = tanhf(sval[tid]);
    const float* rr = &repl[(size_t)rowi*20];
    float4 r0 = *(const float4*)(rr),   r1 = *(const float4*)(rr+4);
    float4 r2 = *(const float4*)(rr+8), r3 = *(const float4*)(rr+12);
    const float vv[16] = {tv*r0.x,tv*r0.y,tv*r0.z,tv*r0.w,
                          tv*r1.x,tv*r1.y,tv*r1.z,tv*r1.w,
                          tv*r2.x,tv*r2.y,tv*r2.z,tv*r2.w,
                          tv*r3.x,tv*r3.y,tv*r3.z,tv*r3.w};
    float* o = &fx[(size_t)tid*20];
    *(float4*)(o+0)  = make_float4(vv[0],vv[1],vv[2],vv[3]);
    *(float4*)(o+4)  = make_float4(vv[4],vv[5],vv[6],vv[7]);
    *(float4*)(o+8)  = make_float4(vv[8],vv[9],vv[10],vv[11]);
    *(float4*)(o+12) = make_float4(vv[12],vv[13],vv[14],vv[15]);
    #pragma unroll
    for (int q=0;q<16;q++) attx1T[q*241 + tid] = vv[q];
  }
  __syncthreads();

  // ---- PH: waves 0-11 subadj gather || waves 12-15 Wg3 staging + att1 ----
  if (wave < 12){
    int jc[4];
    #pragma unroll
    for (int c=0;c<4;c++){
      const int j = lane + 64*c;
      jc[c] = (j < K2_) ? il[j] : 0;
    }
    #pragma unroll
    for (int p=0;p<20;p++){
      const int r = wave*20 + p;
      const float* row = abase + (size_t)il[r]*512;
      float* orow = adjnew + ((size_t)b*K2_ + r)*K2_;
      #pragma unroll
      for (int c=0;c<4;c++){
        const int j = lane + 64*c;
        if (j < K2_) orow[j] = row[jc[c]];
      }
    }
  } else {
    const int t4 = tid - 768;
    for (int idx = t4; idx < 1536; idx += 256) wl[idx] = Wg3[idx];
    if (t4 < 96) bl[t4] = bg3[t4];
    if (t4 < 16) pwl[t4] = p2w[t4];
    #pragma unroll
    for (int t=0;t<4;t++){
      const int q = (wave-12)*4 + t;
      float v[4];
      #pragma unroll
      for (int r=0;r<4;r++){
        const int idx = lane + 64*r;
        v[r] = (idx < K2_) ? attx1T[q*241 + idx] : NEGINF;
      }
      wave_sort_desc<4>(v, lane);
      if (lane < 40) attl[q*120 + 40 + lane] = v[0];
    }
  }
  __syncthreads();

  // ---- PI: gemm240 + matrix gate -> repl, xv(=x4) ----
  {
    const int g = tid >> 2, sub = tid & 3;
    if (g < K2_){
      const int m = g;
      const float* r0 = adjnew + ((size_t)b*K2_ + m)*K2_;
      float acc[16];
      #pragma unroll
      for (int q=0;q<16;q++) acc[q] = 0.f;
      for (int i=0;i<15;i++){
        const int kk = i*16 + sub*4;
        float4 a4 = *(const float4*)(r0 + kk);
        const float av[4] = {a4.x, a4.y, a4.z, a4.w};
        #pragma unroll
        for (int c=0;c<4;c++){
          const float* fr = &fx[(size_t)(kk + c)*20];
          float4 q0 = *(const float4*)(fr);
          float4 q1 = *(const float4*)(fr+4);
          float4 q2 = *(const float4*)(fr+8);
          float4 q3 = *(const float4*)(fr+12);
          const float qv[16] = {q0.x,q0.y,q0.z,q0.w, q1.x,q1.y,q1.z,q1.w,
                                q2.x,q2.y,q2.z,q2.w, q3.x,q3.y,q3.z,q3.w};
          #pragma unroll
          for (int q=0;q<16;q++)
            acc[q] = fmaf(av[c], qv[q], acc[q]);
        }
      }
      #pragma unroll
      for (int q=0;q<16;q++){
        float v = acc[q];
        v += __shfl_xor(v, 1);
        v += __shfl_xor(v, 2);
        acc[q] = v;
      }
      float x[16];
      {
        const float* xr = &fx[(size_t)m*20];
        float4 x0 = *(const float4*)(xr),   x1 = *(const float4*)(xr+4);
        float4 x2v = *(const float4*)(xr+8), x3 = *(const float4*)(xr+12);
        x[0]=x0.x; x[1]=x0.y; x[2]=x0.z; x[3]=x0.w;
        x[4]=x1.x; x[5]=x1.y; x[6]=x1.z; x[7]=x1.w;
        x[8]=x2v.x; x[9]=x2v.y; x[10]=x2v.z; x[11]=x2v.w;
        x[12]=x3.x; x[13]=x3.y; x[14]=x3.z; x[15]=x3.w;
      }
      float rx[16];
      #pragma unroll
      for (int q=0;q<16;q++){
        const float s1 = bl[32+q] + bl[48+q]
                       + dot16(acc, &wl[512 + q*16]) + dot16(x, &wl[768 + q*16]);
        rx[q] = sigf(s1) * x[q];
      }
      float xp = 0.f;
      #pragma unroll
      for (int j=0;j<4;j++){
        const int q = sub*4 + j;
        const float s0 = bl[q] + bl[16+q]
                       + dot16(acc, &wl[q*16]) + dot16(x, &wl[256 + q*16]);
        const float z = sigf(s0);
        const float s = bl[64+q] + bl[80+q]
                      + dot16(acc, &wl[1024 + q*16]) + dot16(rx, &wl[1280 + q*16]);
        const float h = fmaxf(s, 0.f);
        const float o = h*z + x[q]*(1.f - z);
        repl[(size_t)m*20 + q] = o;
        xp = fmaf(o, pwl[q], xp);
      }
      xp += __shfl_xor(xp,1); xp += __shfl_xor(xp,2);
      if (sub == 0) xv[m] = xp + p2b[0];
    }
  }
  __syncthreads();

  // ---- PJ: score2 ----
  {
    const int g = tid >> 2, sub = tid & 3;
    const float w0=wg4[0],w1=wg4[1],w2=wg4[2],w3=wg4[3],w4=wg4[4],w5=wg4[5];
    const float c0=bg4[0],c1=bg4[1],c2=bg4[2],c3=bg4[3],c4=bg4[4],c5=bg4[5];
    if (g < K2_){
      const float* row = adjnew + ((size_t)b*K2_ + g)*K2_;
      float s = 0.f;
      #pragma unroll
      for (int i=0;i<15;i++){
        const int kk = i*16 + sub*4;
        float4 a4 = *(const float4*)(row + kk);
        float4 xq = *(const float4*)(&xv[kk]);
        s = fmaf(a4.x,xq.x,s); s = fmaf(a4.y,xq.y,s);
        s = fmaf(a4.z,xq.z,s); s = fmaf(a4.w,xq.w,s);
      }
      s += __shfl_xor(s,1); s += __shfl_xor(s,2);
      if (sub == 0){
        const float x = xv[g];
        const float z = sigf(fmaf(s,w0,c0) + fmaf(x,w1,c1));
        const float r = sigf(fmaf(s,w2,c2) + fmaf(x,w3,c3));
        const float h = fmaxf(fmaf(s,w4,c4) + fmaf(r*x,w5,c5), 0.f);
        sval[g] = h*z + x*(1.f - z);
        sidx[g] = g;
      }
    }
    if (tid >= 960 && tid < 976){
      sval[K2_ + tid - 960] = NEGINF;
      sidx[K2_ + tid - 960] = 0x7fffffff;
    }
  }
  hybrid_sort<256>(sval, sidx);

  // ---- PL: gather att_x2 into attx2T (reuse attx1T) ----
  if (tid < K4_){
    const int rowi = sidx[tid];
    const float tv = tanhf(sval[tid]);
    const float* rr = &repl[(size_t)rowi*20];
    float4 r0 = *(const float4*)(rr),   r1 = *(const float4*)(rr+4);
    float4 r2 = *(const float4*)(rr+8), r3 = *(const float4*)(rr+12);
    const float vv[16] = {tv*r0.x,tv*r0.y,tv*r0.z,tv*r0.w,
                          tv*r1.x,tv*r1.y,tv*r1.z,tv*r1.w,
                          tv*r2.x,tv*r2.y,tv*r2.z,tv*r2.w,
                          tv*r3.x,tv*r3.y,tv*r3.z,tv*r3.w};
    #pragma unroll
    for (int q=0;q<16;q++) attx1T[q*241 + tid] = vv[q];
  }
  __syncthreads();

  // ---- PM: att2 top-40 (one q per wave) ----
  {
    const int q = wave;
    float v[4];
    #pragma unroll
    for (int r=0;r<4;r++){
      const int idx = lane + 64*r;
      v[r] = (idx < K4_) ? attx1T[q*241 + idx] : NEGINF;
    }
    wave_sort_desc<4>(v, lane);
    if (lane < 40) attl[q*120 + 80 + lane] = v[0];
  }
  __syncthreads();

  // ---- PN: MLP (weights from global/L2) + gated softmax + sum ----
  {
    const int q = tid >> 6, u = tid & 63;
    float acc = l1b[u];
    const float* wrow = l1w + (size_t)u*120;
    #pragma unroll
    for (int k4=0;k4<30;k4++){
      float4 av = *(const float4*)(&attl[q*120 + k4*4]);
      float4 wv = *(const float4*)(wrow + k4*4);
      acc = fmaf(av.x,wv.x,acc); acc = fmaf(av.y,wv.y,acc);
      acc = fmaf(av.z,wv.z,acc); acc = fmaf(av.w,wv.w,acc);
    }
    rel1[q*64 + u] = fmaxf(acc, 0.f);
  }
  __syncthreads();
  if (tid < 512){
    const int q = tid >> 5, u = tid & 31;
    float acc = l2b[u];
    const float* wrow = l2w + (size_t)u*64;
    #pragma unroll
    for (int k4=0;k4<16;k4++){
      float4 av = *(const float4*)(&rel1[q*64 + k4*4]);
      float4 wv = *(const float4*)(wrow + k4*4);
      acc = fmaf(av.x,wv.x,acc); acc = fmaf(av.y,wv.y,acc);
      acc = fmaf(av.z,wv.z,acc); acc = fmaf(av.w,wv.w,acc);
    }
    rel2[q*32 + u] = fmaxf(acc, 0.f);
  }
  __syncthreads();
  if (tid < 16){
    float acc = l3b[0];
    #pragma unroll
    for (int k=0;k<32;k++) acc = fmaf(rel2[tid*32+k], l3w[k], acc);
    const float gv = fmaf(idf[(size_t)b*16 + tid], gw[0], gb[0]);
    float mx = gv;
    mx = fmaxf(mx, __shfl_xor(mx, 1));
    mx = fmaxf(mx, __shfl_xor(mx, 2));
    mx = fmaxf(mx, __shfl_xor(mx, 4));
    mx = fmaxf(mx, __shfl_xor(mx, 8));
    const float e = __expf(gv - mx);
    float se = e;
    se += __shfl_xor(se, 1); se += __shfl_xor(se, 2);
    se += __shfl_xor(se, 4); se += __shfl_xor(se, 8);
    float val = acc * (e / se);
    val += __shfl_xor(val, 1); val += __shfl_xor(val, 2);
    val += __shfl_xor(val, 4); val += __shfl_xor(val, 8);
    if (tid == 0) outp[b] = val;
  }
}

extern "C" void kernel_launch(void* const* d_in, const int* in_sizes, int n_in,
                              void* d_out, int out_size, void* d_ws, size_t ws_size,
                              hipStream_t stream)
{
  const float* emb  = (const float*)d_in[0];
  const int*   qtok = (const int*)d_in[1];
  const int*   dtok = (const int*)d_in[2];
  const int*   dids = (const int*)d_in[3];
  const float* dadj = (const float*)d_in[4];
  const float* idf  = (const float*)d_in[5];
  const float* Wg1  = (const float*)d_in[6];
  const float* bg1  = (const float*)d_in[7];
  const float* wg2  = (const float*)d_in[8];
  const float* bg2  = (const float*)d_in[9];
  const float* Wg3  = (const float*)d_in[10];
  const float* bg3  = (const float*)d_in[11];
  const float* wg4  = (const float*)d_in[12];
  const float* bg4  = (const float*)d_in[13];
  const float* p1w  = (const float*)d_in[14];
  const float* p1b  = (const float*)d_in[15];
  const float* p2w  = (const float*)d_in[16];
  const float* p2b  = (const float*)d_in[17];
  const float* l1w  = (const float*)d_in[18];
  const float* l1b  = (const float*)d_in[19];
  const float* l2w  = (const float*)d_in[20];
  const float* l2b  = (const float*)d_in[21];
  const float* l3w  = (const float*)d_in[22];
  const float* l3b  = (const float*)d_in[23];
  const float* gw   = (const float*)d_in[24];
  const float* gb   = (const float*)d_in[25];
  float* out = (float*)d_out;

  float* adjnew = (float*)d_ws;   // B*240*240 floats = 56 MB

  const size_t lds_bytes = 36608u * 4u;   // 146432 B

  k_all<<<B_, 1024, lds_bytes, stream>>>(
      emb, qtok, dtok, dids, dadj,
      Wg1, bg1, p1w, p1b, wg2, bg2, Wg3, bg3, p2w, p2b, wg4, bg4,
      l1w, l1b, l2w, l2b, l3w, l3b, idf, gw, gb,
      adjnew, out);
}